// Round 3
// baseline (130.996 us; speedup 1.0000x reference)
//
#include <hip/hip_runtime.h>

// SimpleEdgeModel round 9: producer/consumer wave specialization.
// R8 post-mortem: weights-in-LDS worked but the LDS pipe became the wall:
// per wave-u 96 ds_read_b128 + 16 writes ~= 1344cy; x8 waves x4u x2blk =
// 86k DS-cy/CU vs 40k MFMA-cy/SIMD (matches 42.4us, MfmaUtil 32%).  The
// weight frags (64 of those 96 reads) are IDENTICAL for every wave/u/block
// -> make them stationary.  Both layers don't fit in 256 VGPRs, so split
// roles: waves 0-3 = layer-2 producers (W2 from LDS, 32KB), waves 4-7 =
// layer-3 consumers (W3 in 128 VGPRs, ZERO weight reads).  e2 handoff via
// the existing double-buffered LDS slots (8KB/producer x2), one
// __syncthreads per i-step.  New DS budget/CU-step ~3.5k cy < 5.0k MFMA
// cy/SIMD -> MFMA-bound.  16 i per block, 17 steps (94% pipeline fill),
// grid = 256 blocks = exactly 1/CU.  gj hoist dropped: w3's live range
// spans the loop for ALL waves (regalloc is role-blind), so producers
// carry those 128 regs too; peak must stay < 256.
// s_setprio around MFMA: role-split waves = T5's confirmed regime.
//
// out[b,i,j] = Wo.relu(W3^T.relu(W2^T.relu(g_j+bc1-g_i)+bc2)+bc3)+bo
// g = nodeMLP(x)@Wc1.

typedef _Float16 half_t;
typedef __attribute__((ext_vector_type(2))) _Float16 f16x2;
typedef __attribute__((ext_vector_type(8))) _Float16 f16x8;
typedef __attribute__((ext_vector_type(4))) float f32x4;

// ws layout:
//   gh  : 1024*128 f16 @ 0        = f16(g)
//   gbh : 1024*128 f16 @ 262144   = f16(g + bc1)
//   W2T : 16384 f16    @ 524288   (frag-packed Wc2, (nt*4+ks) order)
//   W3T : 16384 f16    @ 557056

// ---------------------------------------------------------------------------
// prep: blocks 0..255 node MLP (4 nodes/block); 256..271 weight frag pack.
// Frag (nt,ks), lane L=q*16+c, elem e  <-  Wsrc[32ks+8q+e][16nt+c].
// ---------------------------------------------------------------------------
__global__ __launch_bounds__(256) void prep_kernel(
    const float* __restrict__ x, const float* __restrict__ Wa, const float* __restrict__ ba,
    const float* __restrict__ Wb, const float* __restrict__ bb, const float* __restrict__ Wc1,
    const float* __restrict__ bc1, const float* __restrict__ Wc2, const float* __restrict__ Wc3,
    half_t* __restrict__ gh, half_t* __restrict__ gbh,
    half_t* __restrict__ W2T, half_t* __restrict__ W3T)
{
  const int t = threadIdx.x;
  if (blockIdx.x >= 256) {
    const int bid = blockIdx.x - 256;            // layer(1b) x ntile(3b)
    const int layer = bid >> 3, nt = bid & 7;
    const int ks = t >> 6, L = t & 63, q = L >> 4, cc = L & 15;
    const float* src = layer ? Wc3 : Wc2;
    half_t* dst = layer ? W3T : W2T;
    f16x8 v;
    #pragma unroll
    for (int e = 0; e < 8; e++)
      v[e] = (half_t)src[(32 * ks + 8 * q + e) * 128 + 16 * nt + cc];
    *(f16x8*)(dst + (nt * 4 + ks) * 512 + L * 8) = v;   // ks-frags contiguous per nt
    return;
  }
  __shared__ float sx[64 * 6];
  __shared__ float sh1[128 * 6];
  __shared__ float sh2[128 * 6];
  const int n0 = blockIdx.x * 4;
  const int col = t & 127, hf = t >> 7;

  sx[(t & 63) * 6 + (t >> 6)] = x[(n0 + (t >> 6)) * 64 + (t & 63)];
  __syncthreads();

  float a0 = ba[col], a1 = a0;
  #pragma unroll
  for (int cc = 0; cc < 64; cc++) {
    const float wv = Wa[cc * 128 + col];
    const float2 xv = *(const float2*)(sx + cc * 6 + hf * 2);
    a0 = fmaf(xv.x, wv, a0); a1 = fmaf(xv.y, wv, a1);
  }
  *(float2*)(sh1 + col * 6 + hf * 2) = make_float2(fmaxf(a0, 0.f), fmaxf(a1, 0.f));
  __syncthreads();

  float b0 = bb[col], b1 = b0;
  #pragma unroll
  for (int k = 0; k < 128; k++) {
    const float wv = Wb[k * 128 + col];
    const float2 hv = *(const float2*)(sh1 + k * 6 + hf * 2);
    b0 = fmaf(hv.x, wv, b0); b1 = fmaf(hv.y, wv, b1);
  }
  *(float2*)(sh2 + col * 6 + hf * 2) = make_float2(fmaxf(b0, 0.f), fmaxf(b1, 0.f));
  __syncthreads();

  float c0 = 0.f, c1 = 0.f;
  #pragma unroll
  for (int k = 0; k < 128; k++) {
    const float wv = Wc1[k * 128 + col];
    const float2 hv = *(const float2*)(sh2 + k * 6 + hf * 2);
    c0 = fmaf(hv.x, wv, c0); c1 = fmaf(hv.y, wv, c1);
  }
  const float bv = bc1[col];
  const int r0 = n0 + hf * 2;
  gh [(r0 + 0) * 128 + col] = (half_t)c0;
  gh [(r0 + 1) * 128 + col] = (half_t)c1;
  gbh[(r0 + 0) * 128 + col] = (half_t)(c0 + bv);
  gbh[(r0 + 1) * 128 + col] = (half_t)(c1 + bv);
}

// ---------------------------------------------------------------------------
// edge kernel. 256 blocks x 512 threads = b(1b) x jq(2b) x ichunk(5b, 16 i).
// Waves 0-3: layer-2 producers (32 j-rows each, W2 from LDS).
// Waves 4-7: layer-3 consumers (same j-rows, W3 in 128 VGPRs).
// 17-step software pipeline: producer fills slot step&1, consumer drains
// slot (step-1)&1; one __syncthreads per step.
// ---------------------------------------------------------------------------
static __device__ inline f16x8 relu_sub8(f16x8 a, f16x8 b) {
  f16x8 d = a - b;
  const f16x8 z = {};
  return __builtin_elementwise_max(d, z);
}

__global__ __launch_bounds__(512, 2)
void edge_kernel(
    const half_t* __restrict__ gh, const half_t* __restrict__ gbh,
    const half_t* __restrict__ W2T, const half_t* __restrict__ W3T,
    const float* __restrict__ bc2, const float* __restrict__ bc3,
    const float* __restrict__ Wo, const float* __restrict__ bo,
    float* __restrict__ out)
{
  __shared__ __align__(16) half_t sW2[16384];        // 32 KB  (producer weights)
  __shared__ __align__(16) float  sBf[384];          // bc2 | bc3 | Wo (1.5 KB)
  __shared__ __align__(16) half_t sE[4 * 2 * 4096];  // 64 KB: [producer][slot][e2]

  const int t = threadIdx.x, lane = t & 63, w = t >> 6;
  const int c = lane & 15, q = lane >> 4;
  const int bid = blockIdx.x;
  const int b = bid >> 7, jq = (bid >> 5) & 3, ic = bid & 31;
  const int i0 = ic * 16;
  const bool producer = (w < 4);
  const int pw = producer ? w : (w - 4);
  const int j0w = jq * 128 + pw * 32;

  // ---- stage W2 + biases into LDS (all 512 threads) ----
  #pragma unroll
  for (int k = 0; k < 4; k++) {
    const int off = (k * 512 + t) * 8;
    *(f16x8*)(sW2 + off) = *(const f16x8*)(W2T + off);
  }
  if (t < 384) sBf[t] = (t < 128) ? bc2[t] : ((t < 256) ? bc3[t - 128] : Wo[t - 256]);

  const float bo0 = bo[0];
  // LDS pack address (halfs): ((q>>1)*16+c)*8 + (q&1)*4; +256 halfs when nt odd
  const int packoff = ((q >> 1) * 16 + c) * 8 + (q & 1) * 4;
  const int rdoff = lane * 8;

  // consumers: W3 stationary in 128 VGPRs (frag order matches prep pack)
  f16x8 w3[8][4];
  if (!producer) {
    #pragma unroll
    for (int nt = 0; nt < 8; nt++)
      #pragma unroll
      for (int ks = 0; ks < 4; ks++)
        w3[nt][ks] = *(const f16x8*)(W3T + (nt * 4 + ks) * 512 + rdoff);
  }
  __syncthreads();

  #pragma unroll 1
  for (int step = 0; step < 17; ++step) {
    if (producer) {
      if (step < 16) {
        const int i = i0 + step;
        // ---- phase A: e1[ks][jt] (gj re-read per step: keeps VGPR peak <256) ----
        f16x8 e1[4][2];
        {
          f16x8 gih[4];
          #pragma unroll
          for (int ks = 0; ks < 4; ks++)
            gih[ks] = *(const f16x8*)(gh + (size_t)(b * 512 + i) * 128 + ks * 32 + q * 8);
          #pragma unroll
          for (int ks = 0; ks < 4; ks++)
            #pragma unroll
            for (int jt = 0; jt < 2; jt++) {
              const f16x8 gj = *(const f16x8*)(gbh + (size_t)(b * 512 + j0w + jt * 16 + c) * 128 + ks * 32 + q * 8);
              e1[ks][jt] = relu_sub8(gj, gih[ks]);
            }
        }
        // ---- phase B: layer 2, W2 from LDS, pack e2 -> slot step&1 ----
        half_t* sEw = sE + (pw * 2 + (step & 1)) * 4096;
        #pragma unroll
        for (int nt = 0; nt < 8; nt++) {
          f16x8 wf[4];
          #pragma unroll
          for (int ks = 0; ks < 4; ks++)
            wf[ks] = *(const f16x8*)(sW2 + nt * 2048 + ks * 512 + rdoff);
          const f32x4 b2 = *(const f32x4*)(sBf + nt * 16 + q * 4);
          f32x4 acc[2] = {b2, b2};
          __builtin_amdgcn_s_setprio(1);
          #pragma unroll
          for (int ks = 0; ks < 4; ks++)
            #pragma unroll
            for (int jt = 0; jt < 2; jt++)
              acc[jt] = __builtin_amdgcn_mfma_f32_16x16x32_f16(wf[ks], e1[ks][jt], acc[jt], 0, 0, 0);
          __builtin_amdgcn_s_setprio(0);
          const int po = ((nt >> 1) * 512) + packoff + (nt & 1) * 256;   // ks3 slot base
          #pragma unroll
          for (int jt = 0; jt < 2; jt++) {
            const f32x4 v = acc[jt];
            f16x2 h01, h23;
            h01[0] = (half_t)fmaxf(v[0], 0.f); h01[1] = (half_t)fmaxf(v[1], 0.f);
            h23[0] = (half_t)fmaxf(v[2], 0.f); h23[1] = (half_t)fmaxf(v[3], 0.f);
            uint2 uv;
            uv.x = __builtin_bit_cast(unsigned int, h01);
            uv.y = __builtin_bit_cast(unsigned int, h23);
            *(uint2*)(sEw + jt * 2048 + po) = uv;    // (jt*4+ks3)*512 = jt*2048+ks3*512
          }
        }
      }
    } else {
      if (step >= 1) {
        const int i = i0 + step - 1;
        // ---- phase C: layer 3; be from slot (step-1)&1, W3 from regs ----
        const half_t* sEc = sE + (pw * 2 + ((step - 1) & 1)) * 4096;
        f16x8 be[4][2];
        #pragma unroll
        for (int ks3 = 0; ks3 < 4; ks3++)
          #pragma unroll
          for (int jt = 0; jt < 2; jt++)
            be[ks3][jt] = *(const f16x8*)(sEc + (jt * 4 + ks3) * 512 + rdoff);

        float p[2] = {0.f, 0.f};
        #pragma unroll
        for (int nt = 0; nt < 8; nt++) {
          const f32x4 b3 = *(const f32x4*)(sBf + 128 + nt * 16 + q * 4);
          f32x4 acc[2] = {b3, b3};
          __builtin_amdgcn_s_setprio(1);
          #pragma unroll
          for (int ks3 = 0; ks3 < 4; ks3++)
            #pragma unroll
            for (int jt = 0; jt < 2; jt++)
              acc[jt] = __builtin_amdgcn_mfma_f32_16x16x32_f16(w3[nt][ks3], be[ks3][jt], acc[jt], 0, 0, 0);
          __builtin_amdgcn_s_setprio(0);
          const f32x4 wo = *(const f32x4*)(sBf + 256 + nt * 16 + q * 4);
          #pragma unroll
          for (int jt = 0; jt < 2; jt++)
            #pragma unroll
            for (int r = 0; r < 4; r++)
              p[jt] = fmaf(fmaxf(acc[jt][r], 0.f), wo[r], p[jt]);
        }
        // ---- epilogue: reduce over q (rows n3 split across q), store ----
        #pragma unroll
        for (int jt = 0; jt < 2; jt++) {
          p[jt] += __shfl_xor(p[jt], 16, 64);
          p[jt] += __shfl_xor(p[jt], 32, 64);
        }
        if (q == 0) {
          const size_t base = ((size_t)(b * 512 + i)) * 512 + j0w;
          #pragma unroll
          for (int jt = 0; jt < 2; jt++)
            out[base + jt * 16 + c] = p[jt] + bo0;
        }
      }
    }
    __syncthreads();
  }
}

// ---------------------------------------------------------------------------
extern "C" void kernel_launch(void* const* d_in, const int* in_sizes, int n_in,
                              void* d_out, int out_size, void* d_ws, size_t ws_size,
                              hipStream_t stream)
{
  const float* x   = (const float*)d_in[0];
  const float* Wa  = (const float*)d_in[1];
  const float* ba  = (const float*)d_in[2];
  const float* Wb  = (const float*)d_in[3];
  const float* bb  = (const float*)d_in[4];
  const float* Wc1 = (const float*)d_in[5];
  const float* bc1 = (const float*)d_in[6];
  const float* Wc2 = (const float*)d_in[7];
  const float* bc2 = (const float*)d_in[8];
  const float* Wc3 = (const float*)d_in[9];
  const float* bc3 = (const float*)d_in[10];
  const float* Wo  = (const float*)d_in[11];
  const float* bo  = (const float*)d_in[12];
  float* out = (float*)d_out;

  char* ws = (char*)d_ws;
  half_t* gh  = (half_t*)ws;                      // 256 KB
  half_t* gbh = (half_t*)(ws + 262144);           // 256 KB
  half_t* W2T = (half_t*)(ws + 524288);           // 32 KB
  half_t* W3T = (half_t*)(ws + 557056);           // 32 KB

  prep_kernel<<<272, 256, 0, stream>>>(x, Wa, ba, Wb, bb, Wc1, bc1, Wc2, Wc3,
                                       gh, gbh, W2T, W3T);
  edge_kernel<<<256, 512, 0, stream>>>(gh, gbh, W2T, W3T, bc2, bc3, Wo, bo, out);
}